// Round 15
// baseline (134.011 us; speedup 1.0000x reference)
//
#include <hip/hip_runtime.h>
#include <cstddef>
#include <cstdint>

#define BB 4
#define SS 2048
#define HH 1024
#define NH 16
#define HD 64

typedef _Float16 half8 __attribute__((ext_vector_type(8)));
typedef _Float16 half4v __attribute__((ext_vector_type(4)));
typedef float f32x4 __attribute__((ext_vector_type(4)));

#define KSCALE 0.1803368801111f   /* 0.125 * log2(e): folded into Q at projection */

__device__ __forceinline__ void gload_lds16(const _Float16* g, char* l) {
    __builtin_amdgcn_global_load_lds(
        (const __attribute__((address_space(1))) void*)g,
        (__attribute__((address_space(3))) void*)l, 16, 0, 0);
}

// ---------------- per-batch mask prefix scan -> valid + invalid index maps -------
__global__ __launch_bounds__(256)
void scan_mask(const int* __restrict__ mk, int* __restrict__ vidx,
               int* __restrict__ ividx, int* __restrict__ cnt)
{
    __shared__ int ps[256];
    const int b = blockIdx.x, t = threadIdx.x;
    int flag[8], s = 0;
#pragma unroll
    for (int k = 0; k < 8; ++k) { flag[k] = (mk[(b << 11) + t * 8 + k] == 0); s += flag[k]; }
    ps[t] = s;
    __syncthreads();
    for (int off = 1; off < 256; off <<= 1) {
        const int add = (t >= off) ? ps[t - off] : 0;
        __syncthreads();
        ps[t] += add;
        __syncthreads();
    }
    int posv = ps[t] - s;   // exclusive prefix of valid
#pragma unroll
    for (int k = 0; k < 8; ++k) {
        const int gidx = t * 8 + k;
        if (flag[k]) vidx[(b << 11) + posv++] = gidx;
        else         ividx[(b << 11) + (gidx - posv)] = gidx;
    }
    if (t == 255) cnt[b] = ps[255];
}

// ---------------- fused: gather valid x rows -> fp16 + zero invalid out rows -----
__global__ __launch_bounds__(256)
void prep_rows(const float* __restrict__ x, const int* __restrict__ vidx,
               const int* __restrict__ ividx, const int* __restrict__ cnt,
               _Float16* __restrict__ xc, float* __restrict__ out)
{
    const int row = blockIdx.x;            // 0..8191
    const int b = row >> 11, i = row & 2047;
    const int t = threadIdx.x;
    const int cb = cnt[b];
    half4v hv = (half4v){0, 0, 0, 0};
    if (i < cb) {
        const float4 v = ((const float4*)(x + (size_t)((b << 11) + vidx[row]) * HH))[t];
        hv[0] = (_Float16)v.x; hv[1] = (_Float16)v.y;
        hv[2] = (_Float16)v.z; hv[3] = (_Float16)v.w;
    }
    ((half4v*)(xc + (size_t)row * HH))[t] = hv;
    if (i < SS - cb) {
        float* p = out + (size_t)((b << 11) + ividx[row]) * HH;
        ((float4*)p)[t] = make_float4(0.f, 0.f, 0.f, 0.f);
    }
}

// ---------------- weights fp32 -> fp16 (z selects which of 4) --------------------
__global__ __launch_bounds__(256)
void cvt_w(const float* __restrict__ Wq, const float* __restrict__ Wk,
           const float* __restrict__ Wv, const float* __restrict__ Wc,
           _Float16* __restrict__ o)
{
    const float* src = blockIdx.z == 0 ? Wq : blockIdx.z == 1 ? Wk :
                       blockIdx.z == 2 ? Wv : Wc;
    _Float16* dst = o + (size_t)blockIdx.z * (HH * HH);
    const int i = blockIdx.x * 256 + threadIdx.x;
    const float4 v0 = ((const float4*)src)[(size_t)i * 2];
    const float4 v1 = ((const float4*)src)[(size_t)i * 2 + 1];
    half8 hv;
    hv[0] = (_Float16)v0.x; hv[1] = (_Float16)v0.y;
    hv[2] = (_Float16)v0.z; hv[3] = (_Float16)v0.w;
    hv[4] = (_Float16)v1.x; hv[5] = (_Float16)v1.y;
    hv[6] = (_Float16)v1.z; hv[7] = (_Float16)v1.w;
    ((half8*)dst)[i] = hv;
}

// ---------------- 128x128 fp16 MFMA GEMM core (round-8 proven, for gemm_out) -----
__device__ __forceinline__ void gemm_core128(const _Float16* __restrict__ A,
                                             const _Float16* __restrict__ W,
                                             int K, int m0, int n0,
                                             char* As, char* Bs, f32x4 acc[4][4])
{
    const int t = threadIdx.x;
    const int w = t >> 6, lane = t & 63;
    const int ln = lane & 15, g = lane >> 4;
    const int wr = w >> 1, wc = w & 1;

    const int rr0 = w * 16 + (lane >> 2);
    const int rr1 = rr0 + 64;
    const int p   = lane & 3;
    const int sl0 = p ^ ((rr0 >> 1) & 3);
    const int sl1 = p ^ ((rr1 >> 1) & 3);
    const _Float16* ga0 = A + (size_t)(m0 + rr0) * K + sl0 * 8;
    const _Float16* ga1 = A + (size_t)(m0 + rr1) * K + sl1 * 8;
    const _Float16* gb0 = W + (size_t)(n0 + rr0) * K + sl0 * 8;
    const _Float16* gb1 = W + (size_t)(n0 + rr1) * K + sl1 * 8;
    char* dA = As + w * 1024 + lane * 16;
    char* dB = Bs + w * 1024 + lane * 16;

    int offA[4], offB[4];
#pragma unroll
    for (int i = 0; i < 4; ++i) {
        const int ra = wr * 64 + i * 16 + ln;
        offA[i] = ra * 64 + ((g ^ ((ra >> 1) & 3)) << 4);
        const int rb = wc * 64 + i * 16 + ln;
        offB[i] = rb * 64 + ((g ^ ((rb >> 1) & 3)) << 4);
    }

#pragma unroll
    for (int i = 0; i < 4; ++i)
#pragma unroll
        for (int j = 0; j < 4; ++j) acc[i][j] = (f32x4){0.f, 0.f, 0.f, 0.f};

    gload_lds16(ga0, dA);
    gload_lds16(ga1, dA + 4096);
    gload_lds16(gb0, dB);
    gload_lds16(gb1, dB + 4096);
    gload_lds16(ga0 + 32, dA + 8192);
    gload_lds16(ga1 + 32, dA + 8192 + 4096);
    gload_lds16(gb0 + 32, dB + 8192);
    gload_lds16(gb1 + 32, dB + 8192 + 4096);

    const int ns = K / 32;
    for (int k = 0; k < ns; ++k) {
        if (k < ns - 1) { asm volatile("s_waitcnt vmcnt(4)" ::: "memory"); }
        else            { asm volatile("s_waitcnt vmcnt(0)" ::: "memory"); }
        __builtin_amdgcn_s_barrier();
        __builtin_amdgcn_sched_barrier(0);

        const char* Ab = As + ((k & 1) << 13);
        const char* Bb = Bs + ((k & 1) << 13);
        half8 af[4], bf[4];
#pragma unroll
        for (int i = 0; i < 4; ++i) af[i] = *(const half8*)(Ab + offA[i]);
#pragma unroll
        for (int j = 0; j < 4; ++j) bf[j] = *(const half8*)(Bb + offB[j]);

        asm volatile("s_waitcnt lgkmcnt(0)" ::: "memory");
        __builtin_amdgcn_s_barrier();
        __builtin_amdgcn_sched_barrier(0);

        if (k + 2 < ns) {
            const int nb = (k & 1) << 13;
            const int ko = (k + 2) * 32;
            gload_lds16(ga0 + ko, dA + nb);
            gload_lds16(ga1 + ko, dA + nb + 4096);
            gload_lds16(gb0 + ko, dB + nb);
            gload_lds16(gb1 + ko, dB + nb + 4096);
        }
#pragma unroll
        for (int i = 0; i < 4; ++i)
#pragma unroll
            for (int j = 0; j < 4; ++j)
                acc[i][j] = __builtin_amdgcn_mfma_f32_16x16x32_f16(af[i], bf[j], acc[i][j], 0, 0, 0);
    }
}

// ---------------- FUSED QKV GEMM: 256x256 tile, 512 thr, 8 waves (2Mx4N) ---------
__global__ __launch_bounds__(512, 2)
void gemm_qkv(const _Float16* __restrict__ xc, const _Float16* __restrict__ W16,
              const float* __restrict__ bq, const float* __restrict__ bk,
              const float* __restrict__ bv, const int* __restrict__ cnt,
              _Float16* __restrict__ Qh, _Float16* __restrict__ Kh,
              _Float16* __restrict__ Vt)
{
    const int yb = blockIdx.y;                 // 0..31
    const int bI = yb & 3;                     // batch
    const int mt = yb >> 2;                    // m-tile within batch, 0..7
    if (mt * 256 >= ((cnt[bI] + 255) & ~255)) return;
    const int m0 = (bI << 11) + mt * 256;

    __shared__ __align__(16) char As[32768];   // 2 buf x 256 rows x 64B
    __shared__ __align__(16) char Bs[32768];
    const int n0 = blockIdx.x * 256;           // 0..2816; z uniform per block
    const int z = n0 >> 10;
    const float* bias = (z == 0) ? bq : (z == 1) ? bk : bv;

    const int t = threadIdx.x;                 // 0..511
    const int w = t >> 6, lane = t & 63;
    const int ln = lane & 15, g = lane >> 4;
    const int wr = w >> 2, wc = w & 3;         // 2M x 4N wave grid

    const int rr0 = t >> 2;                    // staging rows 0..127
    const int rr1 = rr0 + 128;
    const int p   = t & 3;
    const int sl0 = p ^ ((rr0 >> 1) & 3);
    const int sl1 = p ^ ((rr1 >> 1) & 3);
    const _Float16* ga0 = xc  + (size_t)(m0 + rr0) * HH + sl0 * 8;
    const _Float16* ga1 = xc  + (size_t)(m0 + rr1) * HH + sl1 * 8;
    const _Float16* gb0 = W16 + (size_t)(n0 + rr0) * HH + sl0 * 8;
    const _Float16* gb1 = W16 + (size_t)(n0 + rr1) * HH + sl1 * 8;
    char* dA = As + t * 16;                    // linear dest: row*64 + p*16 = t*16
    char* dB = Bs + t * 16;

    int offA[8], offB[4];
#pragma unroll
    for (int i = 0; i < 8; ++i) {
        const int ra = wr * 128 + i * 16 + ln;
        offA[i] = ra * 64 + ((g ^ ((ra >> 1) & 3)) << 4);
    }
#pragma unroll
    for (int j = 0; j < 4; ++j) {
        const int rb = wc * 64 + j * 16 + ln;
        offB[j] = rb * 64 + ((g ^ ((rb >> 1) & 3)) << 4);
    }

    f32x4 acc[8][4];
#pragma unroll
    for (int i = 0; i < 8; ++i)
#pragma unroll
        for (int j = 0; j < 4; ++j) acc[i][j] = (f32x4){0.f, 0.f, 0.f, 0.f};

    // prologue: T0 -> buf0, T1 -> buf1 (8 loads in flight, 4 per tile)
    gload_lds16(ga0, dA);
    gload_lds16(ga1, dA + 8192);
    gload_lds16(gb0, dB);
    gload_lds16(gb1, dB + 8192);
    gload_lds16(ga0 + 32, dA + 16384);
    gload_lds16(ga1 + 32, dA + 16384 + 8192);
    gload_lds16(gb0 + 32, dB + 16384);
    gload_lds16(gb1 + 32, dB + 16384 + 8192);

    const int ns = HH / 32;                    // 32 K-steps
    for (int k = 0; k < ns; ++k) {
        if (k < ns - 1) { asm volatile("s_waitcnt vmcnt(4)" ::: "memory"); }
        else            { asm volatile("s_waitcnt vmcnt(0)" ::: "memory"); }
        __builtin_amdgcn_s_barrier();
        __builtin_amdgcn_sched_barrier(0);

        const char* Ab = As + ((k & 1) << 14);
        const char* Bb = Bs + ((k & 1) << 14);
        half8 af[8], bf[4];
#pragma unroll
        for (int i = 0; i < 8; ++i) af[i] = *(const half8*)(Ab + offA[i]);
#pragma unroll
        for (int j = 0; j < 4; ++j) bf[j] = *(const half8*)(Bb + offB[j]);

        asm volatile("s_waitcnt lgkmcnt(0)" ::: "memory");
        __builtin_amdgcn_s_barrier();
        __builtin_amdgcn_sched_barrier(0);

        if (k + 2 < ns) {                      // refill buffer just consumed
            const int nb = (k & 1) << 14;
            const int ko = (k + 2) * 32;
            gload_lds16(ga0 + ko, dA + nb);
            gload_lds16(ga1 + ko, dA + nb + 8192);
            gload_lds16(gb0 + ko, dB + nb);
            gload_lds16(gb1 + ko, dB + nb + 8192);
        }
#pragma unroll
        for (int i = 0; i < 8; ++i)
#pragma unroll
            for (int j = 0; j < 4; ++j)
                acc[i][j] = __builtin_amdgcn_mfma_f32_16x16x32_f16(af[i], bf[j], acc[i][j], 0, 0, 0);
    }

    // epilogue
    const int mBase = m0 + wr * 128 + g * 4;
    const int nBase = n0 + wc * 64 + ln;
    if (z < 2) {
        _Float16* O = z ? Kh : Qh;
        const float sc = z ? 1.0f : KSCALE;
#pragma unroll
        for (int j = 0; j < 4; ++j) {
            const int nn = (nBase + j * 16) & 1023;
            const int h = nn >> 6, d = nn & 63;
            const float bvf = bias[nn];
#pragma unroll
            for (int i = 0; i < 8; ++i) {
                const int m = mBase + i * 16;
                const int b = m >> 11, s = m & 2047;
                _Float16* dst = O + (((size_t)(b * NH + h) * SS + s) * HD + d);
#pragma unroll
                for (int r = 0; r < 4; ++r)
                    dst[(size_t)r * HD] = (_Float16)((acc[i][j][r] + bvf) * sc);
            }
        }
    } else {
#pragma unroll
        for (int j = 0; j < 4; ++j) {
            const int nn = (nBase + j * 16) & 1023;
            const int h = nn >> 6, d = nn & 63;
            const float bvf = bias[nn];
#pragma unroll
            for (int i = 0; i < 8; ++i) {
                const int m = mBase + i * 16;
                const int b = m >> 11, s = m & 2047;
                // kappa permutation of s within its 32-key window (r spans s..s+3)
                const int sp = (s & ~31) | (((s >> 2) & 3) << 3) | (((s >> 4) & 1) << 2);
                half4v v;
#pragma unroll
                for (int r = 0; r < 4; ++r) v[r] = (_Float16)(acc[i][j][r] + bvf);
                *(half4v*)(Vt + ((size_t)(b * NH + h) * HD + d) * SS + sp) = v;
            }
        }
    }
}

// ---------------- output GEMM with row scatter back to original order -----------
__global__ __launch_bounds__(256)
void gemm_out(const _Float16* __restrict__ Oc, const _Float16* __restrict__ Wc16,
              const int* __restrict__ cnt, const int* __restrict__ vidx,
              float* __restrict__ C)
{
    const int yb = blockIdx.y;                 // 0..63
    const int bI = yb & 3;
    const int mt = yb >> 2;                    // 0..15
    const int cb = cnt[bI];
    if (mt * 128 >= ((cb + 127) & ~127)) return;
    const int m0 = (bI << 11) + mt * 128;

    __shared__ __align__(16) char As[16384];
    __shared__ __align__(16) char Bs[16384];
    const int n0 = blockIdx.x * 128;

    f32x4 acc[4][4];
    gemm_core128(Oc, Wc16, HH, m0, n0, As, Bs, acc);

    const int t = threadIdx.x;
    const int w = t >> 6, lane = t & 63;
    const int ln = lane & 15, g = lane >> 4;
    const int wr = w >> 1, wc = w & 1;
    const int mBase = m0 + wr * 64 + g * 4;
    const int nBase = n0 + wc * 64 + ln;
#pragma unroll
    for (int i = 0; i < 4; ++i) {
#pragma unroll
        for (int r = 0; r < 4; ++r) {
            const int m = mBase + i * 16 + r;
            const int lm = m & 2047;
            if (lm < cb) {
                const int orig = vidx[m];
                const size_t off = (size_t)((m & ~2047) + orig) * HH + nBase;
#pragma unroll
                for (int j = 0; j < 4; ++j)
                    C[off + j * 16] = acc[i][j][r];
            }
        }
    }
}

// ---------------- fp16-MFMA flash attention: pair-split keys, 2 q-chains/wave ----
// 512 thr = 8 waves = 4 pairs; pair p owns 32 queries (2 independent 16-q
// subtiles qs=0,1 -> two independent dep chains per wave for ILP); wave half
// hf computes key taus 0-1 / 2-3 of each 64-key tile. Block covers 128 q.
// Each kf/vf LDS read now feeds 2 MFMAs (halved LDS + staging traffic per q).
// Counted-vmcnt 3-buffer staging; fixed-ref log2 softmax; kappa-permuted V.
__global__ __launch_bounds__(512, 2)
void attn_mfma(const _Float16* __restrict__ Qh, const _Float16* __restrict__ Kh,
               const _Float16* __restrict__ Vt, const int* __restrict__ cnt,
               _Float16* __restrict__ Oc)
{
    __shared__ __align__(16) char ksm[3][8192];
    __shared__ __align__(16) char vsm[3][8192];

    const int t  = threadIdx.x;
    const int w  = t >> 6, l = t & 63, ln = l & 15, g = l >> 4;
    const int bh = blockIdx.x;                 // bh fastest -> XCD locality
    const int b  = bh >> 4, h = bh & 15;
    const int cb = cnt[b];
    const int q0 = blockIdx.y << 7;            // 128 queries per block
    if (q0 >= cb) return;                      // uniform exit before any barrier
    const int p  = w & 3;                      // pair index -> 32-q group
    const int hf = w >> 2;                     // key-half within each tile
    const int qw = q0 + (p << 5);              // 32-q group base (32-aligned)
    const bool active = (qw < cb);
    const int nt = (cb + 63) >> 6;
    const int jtd = qw >> 6;                   // tile containing the diagonal
    const int relb = (qw & 63) + ln;           // diag key pos base (add qs*16)

    half8 qf[2][2];
    f32x4 oacc[2][4];
    float lrun[2];
    if (active) {
#pragma unroll
        for (int qs = 0; qs < 2; ++qs) {
            const int qg = qw + qs * 16 + ln;
            const _Float16* qp = Qh + ((size_t)bh * SS + qg) * HD + g * 8;
            qf[qs][0] = *(const half8*)qp;
            qf[qs][1] = *(const half8*)(qp + 32);
            lrun[qs] = 0.f;
#pragma unroll
            for (int dd = 0; dd < 4; ++dd) oacc[qs][dd] = (f32x4){0.f, 0.f, 0.f, 0.f};
        }
    }

    const int sr = t >> 3;                     // 0..63
    const int sl = (t & 7) ^ (sr & 7);
    const _Float16* kbase = Kh + ((size_t)bh * SS + sr) * HD + sl * 8;
    const _Float16* vbase = Vt + ((size_t)bh * HD + sr) * SS + sl * 8;

    gload_lds16(kbase, ksm[0] + t * 16);
    gload_lds16(vbase, vsm[0] + t * 16);
    if (nt > 1) {
        gload_lds16(kbase + (size_t)64 * HD, ksm[1] + t * 16);
        gload_lds16(vbase + 64,              vsm[1] + t * 16);
    }

    int cur = 0;
    for (int jt = 0; jt < nt; ++jt) {
        if (jt < nt - 1) { asm volatile("s_waitcnt vmcnt(2) lgkmcnt(0)" ::: "memory"); }
        else             { asm volatile("s_waitcnt vmcnt(0) lgkmcnt(0)" ::: "memory"); }
        __builtin_amdgcn_s_barrier();
        __builtin_amdgcn_sched_barrier(0);

        if (jt + 2 < nt) {                     // refill buffer last read a phase ago
            const int nb = (cur + 2 >= 3) ? cur - 1 : cur + 2;
            const int jn = (jt + 2) << 6;
            gload_lds16(kbase + (size_t)jn * HD, ksm[nb] + t * 16);
            gload_lds16(vbase + jn,              vsm[nb] + t * 16);
        }

        if (active) {
            const int j0 = jt << 6;
            const char* kb = ksm[cur];
            const char* vb = vsm[cur];
            half8 kf[2][2];
#pragma unroll
            for (int tu = 0; tu < 2; ++tu) {
                const int row = (hf * 2 + tu) * 16 + ln;
                const int sw  = (row & 7) << 4;
                const int rb  = row * 128;
                kf[tu][0] = *(const half8*)(kb + ((rb + g * 16)      ^ sw));
                kf[tu][1] = *(const half8*)(kb + ((rb + 64 + g * 16) ^ sw));
            }
            const bool slow = (jt == jtd) | (j0 + 64 > cb);

            f32x4 sa[2][2];
            __builtin_amdgcn_s_setprio(1);
#pragma unroll
            for (int tu = 0; tu < 2; ++tu) {
#pragma unroll
                for (int qs = 0; qs < 2; ++qs) {
                    sa[qs][tu] = (f32x4){0.f, 0.f, 0.f, 0.f};
                    sa[qs][tu] = __builtin_amdgcn_mfma_f32_16x16x32_f16(kf[tu][0], qf[qs][0], sa[qs][tu], 0, 0, 0);
                    sa[qs][tu] = __builtin_amdgcn_mfma_f32_16x16x32_f16(kf[tu][1], qf[qs][1], sa[qs][tu], 0, 0, 0);
                }
            }
            __builtin_amdgcn_s_setprio(0);

            half8 pf[2];
#pragma unroll
            for (int qs = 0; qs < 2; ++qs) {
                float wv[2][4];
#pragma unroll
                for (int tu = 0; tu < 2; ++tu)
#pragma unroll
                    for (int r = 0; r < 4; ++r) {
                        float tv = sa[qs][tu][r];
                        if (slow) {
                            const int kp = (hf * 2 + tu) * 16 + g * 4 + r;
                            if (((jt == jtd) & (kp == relb + qs * 16)) | (j0 + kp >= cb))
                                tv = -1e30f;
                        }
                        wv[tu][r] = exp2f(tv);     // -1e30 -> 0
                    }
                lrun[qs] += ((wv[0][0] + wv[0][1]) + (wv[0][2] + wv[0][3]))
                          + ((wv[1][0] + wv[1][1]) + (wv[1][2] + wv[1][3]));
                half8 pp;
                pp[0] = (_Float16)wv[0][0]; pp[1] = (_Float16)wv[0][1];
                pp[2] = (_Float16)wv[0][2]; pp[3] = (_Float16)wv[0][3];
                pp[4] = (_Float16)wv[1][0]; pp[5] = (_Float16)wv[1][1];
                pp[6] = (_Float16)wv[1][2]; pp[7] = (_Float16)wv[1][3];
                pf[qs] = pp;
            }

            __builtin_amdgcn_s_setprio(1);
#pragma unroll
            for (int dd = 0; dd < 4; ++dd) {
                const int row = dd * 16 + ln;
                const int sw  = (row & 7) << 4;
                const int rb  = row * 128;
                // kappa-permuted V storage: fragment = one contiguous b128
                const half8 vf = *(const half8*)(vb + ((rb + hf * 64 + g * 16) ^ sw));
#pragma unroll
                for (int qs = 0; qs < 2; ++qs)
                    oacc[qs][dd] = __builtin_amdgcn_mfma_f32_16x16x32_f16(vf, pf[qs], oacc[qs][dd], 0, 0, 0);
            }
            __builtin_amdgcn_s_setprio(0);
        }
        cur = (cur + 1 == 3) ? 0 : cur + 1;
    }

    // epilogue: combine pair halves via LDS, one round per qs (softmax linear in keys)
    f32x4* cmo = (f32x4*)ksm;                  // [4 pair][4 dd][64 lane] f32x4 = 16KB
    float*  cml = (float*)vsm;                 // [4 pair][64 lane] float
#pragma unroll
    for (int qs = 0; qs < 2; ++qs) {
        __syncthreads();                       // staging/reads (or prev round) done
        if (active && hf == 1) {
#pragma unroll
            for (int dd = 0; dd < 4; ++dd) cmo[(p * 4 + dd) * 64 + l] = oacc[qs][dd];
            cml[p * 64 + l] = lrun[qs];
        }
        __syncthreads();
        if (active && hf == 0) {
            f32x4 o[4];
#pragma unroll
            for (int dd = 0; dd < 4; ++dd) o[dd] = oacc[qs][dd] + cmo[(p * 4 + dd) * 64 + l];
            float ls = lrun[qs] + cml[p * 64 + l];
            ls += __shfl_xor(ls, 16);
            ls += __shfl_xor(ls, 32);
            const int iq = qw + qs * 16 + ln;
            if (iq < cb) {
                const float inv = (ls > 0.f) ? 1.f / ls : 0.f;
                _Float16* op = Oc + ((size_t)((b << 11) + iq)) * HH + h * HD + g * 4;
#pragma unroll
                for (int dd = 0; dd < 4; ++dd) {
                    half4v hv;
#pragma unroll
                    for (int r = 0; r < 4; ++r) hv[r] = (_Float16)(o[dd][r] * inv);
                    *(half4v*)(op + dd * 16) = hv;
                }
            }
        }
    }
}

// ---------------- launch ----------------
extern "C" void kernel_launch(void* const* d_in, const int* in_sizes, int n_in,
                              void* d_out, int out_size, void* d_ws, size_t ws_size,
                              hipStream_t stream)
{
    (void)in_sizes; (void)n_in; (void)out_size; (void)ws_size;

    const float* x  = (const float*)d_in[0];
    const int*   mk = (const int*)d_in[1];
    const float* Wq = (const float*)d_in[2];
    const float* bq = (const float*)d_in[3];
    const float* Wk = (const float*)d_in[4];
    const float* bk = (const float*)d_in[5];
    const float* Wv = (const float*)d_in[6];
    const float* bv = (const float*)d_in[7];
    const float* Wc = (const float*)d_in[8];
    float* out = (float*)d_out;

    const int M = BB * SS;                    // 8192
    const size_t NE = (size_t)M * HH;
    const size_t NW = (size_t)HH * HH;
    _Float16* xc  = (_Float16*)d_ws;          // NE
    _Float16* W16 = xc + NE;                  // 4*NW (q,k,v contiguous; then c)
    _Float16* Qh  = W16 + 4 * NW;
    _Float16* Kh  = Qh + NE;
    _Float16* Vt  = Kh + NE;
    _Float16* Oc  = Vt + NE;
    int* vidx  = (int*)(Oc + NE);             // M ints
    int* cnt   = vidx + M;                    // 4 ints (+pad)
    int* ividx = cnt + 64;                    // M ints

    scan_mask<<<BB, 256, 0, stream>>>(mk, vidx, ividx, cnt);
    prep_rows<<<M, 256, 0, stream>>>(x, vidx, ividx, cnt, xc, out);
    cvt_w<<<dim3(512, 1, 4), 256, 0, stream>>>(Wq, Wk, Wv, Wc, W16);

    dim3 gq(3 * HH / 256, M / 256);           // (12, 32): actives = low y ids
    gemm_qkv<<<gq, 512, 0, stream>>>(xc, W16, bq, bk, bv, cnt, Qh, Kh, Vt);

    dim3 ga(BB * NH, SS / 128);               // (64, 16): bh fastest, ~half exit
    attn_mfma<<<ga, 512, 0, stream>>>(Qh, Kh, Vt, cnt, Oc);

    dim3 go(HH / 128, M / 128);               // (8, 64): actives = low y ids
    gemm_out<<<go, 256, 0, stream>>>(Oc, W16 + 3 * NW, cnt, vidx, out);
}

// Round 16
// 120.639 us; speedup vs baseline: 1.1108x; 1.1108x over previous
//
#include <hip/hip_runtime.h>
#include <cstddef>
#include <cstdint>

#define BB 4
#define SS 2048
#define HH 1024
#define NH 16
#define HD 64

typedef _Float16 half8 __attribute__((ext_vector_type(8)));
typedef _Float16 half4v __attribute__((ext_vector_type(4)));
typedef float f32x4 __attribute__((ext_vector_type(4)));

#define KSCALE 0.1803368801111f   /* 0.125 * log2(e): folded into Q at projection */

__device__ __forceinline__ void gload_lds16(const _Float16* g, char* l) {
    __builtin_amdgcn_global_load_lds(
        (const __attribute__((address_space(1))) void*)g,
        (__attribute__((address_space(3))) void*)l, 16, 0, 0);
}

// ---------------- per-batch mask prefix scan -> valid + invalid index maps -------
__global__ __launch_bounds__(256)
void scan_mask(const int* __restrict__ mk, int* __restrict__ vidx,
               int* __restrict__ ividx, int* __restrict__ cnt)
{
    __shared__ int ps[256];
    const int b = blockIdx.x, t = threadIdx.x;
    int flag[8], s = 0;
#pragma unroll
    for (int k = 0; k < 8; ++k) { flag[k] = (mk[(b << 11) + t * 8 + k] == 0); s += flag[k]; }
    ps[t] = s;
    __syncthreads();
    for (int off = 1; off < 256; off <<= 1) {
        const int add = (t >= off) ? ps[t - off] : 0;
        __syncthreads();
        ps[t] += add;
        __syncthreads();
    }
    int posv = ps[t] - s;   // exclusive prefix of valid
#pragma unroll
    for (int k = 0; k < 8; ++k) {
        const int gidx = t * 8 + k;
        if (flag[k]) vidx[(b << 11) + posv++] = gidx;
        else         ividx[(b << 11) + (gidx - posv)] = gidx;
    }
    if (t == 255) cnt[b] = ps[255];
}

// ---------------- fused prep: gather x -> fp16, zero invalid out rows, cvt W -----
// Blocks [0, M): row gather + invalid-row zero. Blocks [M, M+2048): weight cvt.
__global__ __launch_bounds__(256)
void prep_rows(const float* __restrict__ x, const int* __restrict__ vidx,
               const int* __restrict__ ividx, const int* __restrict__ cnt,
               _Float16* __restrict__ xc, float* __restrict__ out,
               const float* __restrict__ Wq, const float* __restrict__ Wk,
               const float* __restrict__ Wv, const float* __restrict__ Wc,
               _Float16* __restrict__ W16)
{
    const int t = threadIdx.x;
    const int blk = blockIdx.x;
    if (blk >= BB * SS) {
        const int wi = (blk - BB * SS) * 256 + t;       // half8 idx, 0..524287
        const int z = wi >> 17, idx = wi & 131071;      // 131072 half8 per matrix
        const float* src = z == 0 ? Wq : z == 1 ? Wk : z == 2 ? Wv : Wc;
        _Float16* dst = W16 + (size_t)z * (HH * HH);
        const float4 v0 = ((const float4*)src)[(size_t)idx * 2];
        const float4 v1 = ((const float4*)src)[(size_t)idx * 2 + 1];
        half8 hv;
        hv[0] = (_Float16)v0.x; hv[1] = (_Float16)v0.y;
        hv[2] = (_Float16)v0.z; hv[3] = (_Float16)v0.w;
        hv[4] = (_Float16)v1.x; hv[5] = (_Float16)v1.y;
        hv[6] = (_Float16)v1.z; hv[7] = (_Float16)v1.w;
        ((half8*)dst)[idx] = hv;
        return;
    }
    const int row = blk;                   // 0..8191
    const int b = row >> 11, i = row & 2047;
    const int cb = cnt[b];
    half4v hv = (half4v){0, 0, 0, 0};
    if (i < cb) {
        const float4 v = ((const float4*)(x + (size_t)((b << 11) + vidx[row]) * HH))[t];
        hv[0] = (_Float16)v.x; hv[1] = (_Float16)v.y;
        hv[2] = (_Float16)v.z; hv[3] = (_Float16)v.w;
    }
    ((half4v*)(xc + (size_t)row * HH))[t] = hv;
    if (i < SS - cb) {
        float* p = out + (size_t)((b << 11) + ividx[row]) * HH;
        ((float4*)p)[t] = make_float4(0.f, 0.f, 0.f, 0.f);
    }
}

// ---------------- 128x128 fp16 MFMA GEMM core (round-8 proven, for gemm_out) -----
__device__ __forceinline__ void gemm_core128(const _Float16* __restrict__ A,
                                             const _Float16* __restrict__ W,
                                             int K, int m0, int n0,
                                             char* As, char* Bs, f32x4 acc[4][4])
{
    const int t = threadIdx.x;
    const int w = t >> 6, lane = t & 63;
    const int ln = lane & 15, g = lane >> 4;
    const int wr = w >> 1, wc = w & 1;

    const int rr0 = w * 16 + (lane >> 2);
    const int rr1 = rr0 + 64;
    const int p   = lane & 3;
    const int sl0 = p ^ ((rr0 >> 1) & 3);
    const int sl1 = p ^ ((rr1 >> 1) & 3);
    const _Float16* ga0 = A + (size_t)(m0 + rr0) * K + sl0 * 8;
    const _Float16* ga1 = A + (size_t)(m0 + rr1) * K + sl1 * 8;
    const _Float16* gb0 = W + (size_t)(n0 + rr0) * K + sl0 * 8;
    const _Float16* gb1 = W + (size_t)(n0 + rr1) * K + sl1 * 8;
    char* dA = As + w * 1024 + lane * 16;
    char* dB = Bs + w * 1024 + lane * 16;

    int offA[4], offB[4];
#pragma unroll
    for (int i = 0; i < 4; ++i) {
        const int ra = wr * 64 + i * 16 + ln;
        offA[i] = ra * 64 + ((g ^ ((ra >> 1) & 3)) << 4);
        const int rb = wc * 64 + i * 16 + ln;
        offB[i] = rb * 64 + ((g ^ ((rb >> 1) & 3)) << 4);
    }

#pragma unroll
    for (int i = 0; i < 4; ++i)
#pragma unroll
        for (int j = 0; j < 4; ++j) acc[i][j] = (f32x4){0.f, 0.f, 0.f, 0.f};

    gload_lds16(ga0, dA);
    gload_lds16(ga1, dA + 4096);
    gload_lds16(gb0, dB);
    gload_lds16(gb1, dB + 4096);
    gload_lds16(ga0 + 32, dA + 8192);
    gload_lds16(ga1 + 32, dA + 8192 + 4096);
    gload_lds16(gb0 + 32, dB + 8192);
    gload_lds16(gb1 + 32, dB + 8192 + 4096);

    const int ns = K / 32;
    for (int k = 0; k < ns; ++k) {
        if (k < ns - 1) { asm volatile("s_waitcnt vmcnt(4)" ::: "memory"); }
        else            { asm volatile("s_waitcnt vmcnt(0)" ::: "memory"); }
        __builtin_amdgcn_s_barrier();
        __builtin_amdgcn_sched_barrier(0);

        const char* Ab = As + ((k & 1) << 13);
        const char* Bb = Bs + ((k & 1) << 13);
        half8 af[4], bf[4];
#pragma unroll
        for (int i = 0; i < 4; ++i) af[i] = *(const half8*)(Ab + offA[i]);
#pragma unroll
        for (int j = 0; j < 4; ++j) bf[j] = *(const half8*)(Bb + offB[j]);

        asm volatile("s_waitcnt lgkmcnt(0)" ::: "memory");
        __builtin_amdgcn_s_barrier();
        __builtin_amdgcn_sched_barrier(0);

        if (k + 2 < ns) {
            const int nb = (k & 1) << 13;
            const int ko = (k + 2) * 32;
            gload_lds16(ga0 + ko, dA + nb);
            gload_lds16(ga1 + ko, dA + nb + 4096);
            gload_lds16(gb0 + ko, dB + nb);
            gload_lds16(gb1 + ko, dB + nb + 4096);
        }
#pragma unroll
        for (int i = 0; i < 4; ++i)
#pragma unroll
            for (int j = 0; j < 4; ++j)
                acc[i][j] = __builtin_amdgcn_mfma_f32_16x16x32_f16(af[i], bf[j], acc[i][j], 0, 0, 0);
    }
}

// ---------------- FUSED QKV GEMM: 256x256 tile, 512 thr, 8 waves (2Mx4N) ---------
__global__ __launch_bounds__(512, 2)
void gemm_qkv(const _Float16* __restrict__ xc, const _Float16* __restrict__ W16,
              const float* __restrict__ bq, const float* __restrict__ bk,
              const float* __restrict__ bv, const int* __restrict__ cnt,
              _Float16* __restrict__ Qh, _Float16* __restrict__ Kh,
              _Float16* __restrict__ Vt)
{
    const int yb = blockIdx.y;                 // 0..31
    const int bI = yb & 3;                     // batch
    const int mt = yb >> 2;                    // m-tile within batch, 0..7
    if (mt * 256 >= ((cnt[bI] + 255) & ~255)) return;
    const int m0 = (bI << 11) + mt * 256;

    __shared__ __align__(16) char As[32768];   // 2 buf x 256 rows x 64B
    __shared__ __align__(16) char Bs[32768];
    const int n0 = blockIdx.x * 256;           // 0..2816; z uniform per block
    const int z = n0 >> 10;
    const float* bias = (z == 0) ? bq : (z == 1) ? bk : bv;

    const int t = threadIdx.x;                 // 0..511
    const int w = t >> 6, lane = t & 63;
    const int ln = lane & 15, g = lane >> 4;
    const int wr = w >> 2, wc = w & 3;         // 2M x 4N wave grid

    const int rr0 = t >> 2;                    // staging rows 0..127
    const int rr1 = rr0 + 128;
    const int p   = t & 3;
    const int sl0 = p ^ ((rr0 >> 1) & 3);
    const int sl1 = p ^ ((rr1 >> 1) & 3);
    const _Float16* ga0 = xc  + (size_t)(m0 + rr0) * HH + sl0 * 8;
    const _Float16* ga1 = xc  + (size_t)(m0 + rr1) * HH + sl1 * 8;
    const _Float16* gb0 = W16 + (size_t)(n0 + rr0) * HH + sl0 * 8;
    const _Float16* gb1 = W16 + (size_t)(n0 + rr1) * HH + sl1 * 8;
    char* dA = As + t * 16;                    // linear dest: row*64 + p*16 = t*16
    char* dB = Bs + t * 16;

    int offA[8], offB[4];
#pragma unroll
    for (int i = 0; i < 8; ++i) {
        const int ra = wr * 128 + i * 16 + ln;
        offA[i] = ra * 64 + ((g ^ ((ra >> 1) & 3)) << 4);
    }
#pragma unroll
    for (int j = 0; j < 4; ++j) {
        const int rb = wc * 64 + j * 16 + ln;
        offB[j] = rb * 64 + ((g ^ ((rb >> 1) & 3)) << 4);
    }

    f32x4 acc[8][4];
#pragma unroll
    for (int i = 0; i < 8; ++i)
#pragma unroll
        for (int j = 0; j < 4; ++j) acc[i][j] = (f32x4){0.f, 0.f, 0.f, 0.f};

    // prologue: T0 -> buf0, T1 -> buf1 (8 loads in flight, 4 per tile)
    gload_lds16(ga0, dA);
    gload_lds16(ga1, dA + 8192);
    gload_lds16(gb0, dB);
    gload_lds16(gb1, dB + 8192);
    gload_lds16(ga0 + 32, dA + 16384);
    gload_lds16(ga1 + 32, dA + 16384 + 8192);
    gload_lds16(gb0 + 32, dB + 16384);
    gload_lds16(gb1 + 32, dB + 16384 + 8192);

    const int ns = HH / 32;                    // 32 K-steps
    for (int k = 0; k < ns; ++k) {
        if (k < ns - 1) { asm volatile("s_waitcnt vmcnt(4)" ::: "memory"); }
        else            { asm volatile("s_waitcnt vmcnt(0)" ::: "memory"); }
        __builtin_amdgcn_s_barrier();
        __builtin_amdgcn_sched_barrier(0);

        const char* Ab = As + ((k & 1) << 14);
        const char* Bb = Bs + ((k & 1) << 14);
        half8 af[8], bf[4];
#pragma unroll
        for (int i = 0; i < 8; ++i) af[i] = *(const half8*)(Ab + offA[i]);
#pragma unroll
        for (int j = 0; j < 4; ++j) bf[j] = *(const half8*)(Bb + offB[j]);

        asm volatile("s_waitcnt lgkmcnt(0)" ::: "memory");
        __builtin_amdgcn_s_barrier();
        __builtin_amdgcn_sched_barrier(0);

        if (k + 2 < ns) {                      // refill buffer just consumed
            const int nb = (k & 1) << 14;
            const int ko = (k + 2) * 32;
            gload_lds16(ga0 + ko, dA + nb);
            gload_lds16(ga1 + ko, dA + nb + 8192);
            gload_lds16(gb0 + ko, dB + nb);
            gload_lds16(gb1 + ko, dB + nb + 8192);
        }
#pragma unroll
        for (int i = 0; i < 8; ++i)
#pragma unroll
            for (int j = 0; j < 4; ++j)
                acc[i][j] = __builtin_amdgcn_mfma_f32_16x16x32_f16(af[i], bf[j], acc[i][j], 0, 0, 0);
    }

    // epilogue
    const int mBase = m0 + wr * 128 + g * 4;
    const int nBase = n0 + wc * 64 + ln;
    if (z < 2) {
        _Float16* O = z ? Kh : Qh;
        const float sc = z ? 1.0f : KSCALE;
#pragma unroll
        for (int j = 0; j < 4; ++j) {
            const int nn = (nBase + j * 16) & 1023;
            const int h = nn >> 6, d = nn & 63;
            const float bvf = bias[nn];
#pragma unroll
            for (int i = 0; i < 8; ++i) {
                const int m = mBase + i * 16;
                const int b = m >> 11, s = m & 2047;
                _Float16* dst = O + (((size_t)(b * NH + h) * SS + s) * HD + d);
#pragma unroll
                for (int r = 0; r < 4; ++r)
                    dst[(size_t)r * HD] = (_Float16)((acc[i][j][r] + bvf) * sc);
            }
        }
    } else {
#pragma unroll
        for (int j = 0; j < 4; ++j) {
            const int nn = (nBase + j * 16) & 1023;
            const int h = nn >> 6, d = nn & 63;
            const float bvf = bias[nn];
#pragma unroll
            for (int i = 0; i < 8; ++i) {
                const int m = mBase + i * 16;
                const int b = m >> 11, s = m & 2047;
                // kappa permutation of s within its 32-key window (r spans s..s+3)
                const int sp = (s & ~31) | (((s >> 2) & 3) << 3) | (((s >> 4) & 1) << 2);
                half4v v;
#pragma unroll
                for (int r = 0; r < 4; ++r) v[r] = (_Float16)(acc[i][j][r] + bvf);
                *(half4v*)(Vt + ((size_t)(b * NH + h) * HD + d) * SS + sp) = v;
            }
        }
    }
}

// ---------------- output GEMM with row scatter back to original order -----------
__global__ __launch_bounds__(256)
void gemm_out(const _Float16* __restrict__ Oc, const _Float16* __restrict__ Wc16,
              const int* __restrict__ cnt, const int* __restrict__ vidx,
              float* __restrict__ C)
{
    const int yb = blockIdx.y;                 // 0..63
    const int bI = yb & 3;
    const int mt = yb >> 2;                    // 0..15
    const int cb = cnt[bI];
    if (mt * 128 >= ((cb + 127) & ~127)) return;
    const int m0 = (bI << 11) + mt * 128;

    __shared__ __align__(16) char As[16384];
    __shared__ __align__(16) char Bs[16384];
    const int n0 = blockIdx.x * 128;

    f32x4 acc[4][4];
    gemm_core128(Oc, Wc16, HH, m0, n0, As, Bs, acc);

    const int t = threadIdx.x;
    const int w = t >> 6, lane = t & 63;
    const int ln = lane & 15, g = lane >> 4;
    const int wr = w >> 1, wc = w & 1;
    const int mBase = m0 + wr * 64 + g * 4;
    const int nBase = n0 + wc * 64 + ln;
#pragma unroll
    for (int i = 0; i < 4; ++i) {
#pragma unroll
        for (int r = 0; r < 4; ++r) {
            const int m = mBase + i * 16 + r;
            const int lm = m & 2047;
            if (lm < cb) {
                const int orig = vidx[m];
                const size_t off = (size_t)((m & ~2047) + orig) * HH + nBase;
#pragma unroll
                for (int j = 0; j < 4; ++j)
                    C[off + j * 16] = acc[i][j][r];
            }
        }
    }
}

// ---------------- fp16-MFMA flash attention: pair-split keys (round-14 revert) ---
// 512 thr = 8 waves = 4 pairs; pair p owns 16 queries; hf = key-half per tile.
// Block covers 64 q -> ~1024 active blocks. 2-BUFFER staging (32KB LDS ->
// 5 blocks/CU capacity so all 4 active blocks/CU stay resident); depth-1
// prefetch: vmcnt(0) at phase top drains the tile issued a full phase earlier.
__global__ __launch_bounds__(512, 4)
void attn_mfma(const _Float16* __restrict__ Qh, const _Float16* __restrict__ Kh,
               const _Float16* __restrict__ Vt, const int* __restrict__ cnt,
               _Float16* __restrict__ Oc)
{
    __shared__ __align__(16) char ksm[2][8192];
    __shared__ __align__(16) char vsm[2][8192];

    const int t  = threadIdx.x;
    const int w  = t >> 6, l = t & 63, ln = l & 15, g = l >> 4;
    const int bh = blockIdx.x;                 // bh fastest -> XCD locality
    const int b  = bh >> 4, h = bh & 15;
    const int cb = cnt[b];
    const int q0 = blockIdx.y << 6;            // 64 queries per block
    if (q0 >= cb) return;                      // uniform exit before any barrier
    const int p  = w & 3;                      // pair index -> 16-q group
    const int hf = w >> 2;                     // key-half within each tile
    const int qw = q0 + (p << 4);              // 16-q group base
    const bool active = (qw < cb);
    const int nt = (cb + 63) >> 6;
    const int jtd = qw >> 6;                   // tile containing the diagonal
    const int rel = (qw & 63) + ln;            // diagonal key position in tile

    half8 qf[2];
    f32x4 oacc[4];
    float lrun = 0.f;
    if (active) {
        const int qg = qw + ln;
        const _Float16* qp = Qh + ((size_t)bh * SS + qg) * HD + g * 8;
        qf[0] = *(const half8*)qp;
        qf[1] = *(const half8*)(qp + 32);
#pragma unroll
        for (int dd = 0; dd < 4; ++dd) oacc[dd] = (f32x4){0.f, 0.f, 0.f, 0.f};
    }

    const int sr = t >> 3;                     // 0..63
    const int sl = (t & 7) ^ (sr & 7);
    const _Float16* kbase = Kh + ((size_t)bh * SS + sr) * HD + sl * 8;
    const _Float16* vbase = Vt + ((size_t)bh * HD + sr) * SS + sl * 8;

    // prologue: T0 -> buf0
    gload_lds16(kbase, ksm[0] + t * 16);
    gload_lds16(vbase, vsm[0] + t * 16);

    int cur = 0;
    for (int jt = 0; jt < nt; ++jt) {
        asm volatile("s_waitcnt vmcnt(0) lgkmcnt(0)" ::: "memory");  // T_jt landed
        __builtin_amdgcn_s_barrier();           // all waves past phase jt-1 reads
        __builtin_amdgcn_sched_barrier(0);

        if (jt + 1 < nt) {                      // prefetch T_{jt+1} into other buf
            const int jn = (jt + 1) << 6;
            gload_lds16(kbase + (size_t)jn * HD, ksm[cur ^ 1] + t * 16);
            gload_lds16(vbase + jn,              vsm[cur ^ 1] + t * 16);
        }

        if (active) {
            const int j0 = jt << 6;
            const char* kb = ksm[cur];
            const char* vb = vsm[cur];
            half8 kf[2][2];
#pragma unroll
            for (int tu = 0; tu < 2; ++tu) {
                const int row = (hf * 2 + tu) * 16 + ln;
                const int sw  = (row & 7) << 4;
                const int rb  = row * 128;
                kf[tu][0] = *(const half8*)(kb + ((rb + g * 16)      ^ sw));
                kf[tu][1] = *(const half8*)(kb + ((rb + 64 + g * 16) ^ sw));
            }
            const bool slow = (jt == jtd) | (j0 + 64 > cb);

            f32x4 sa[2];
            __builtin_amdgcn_s_setprio(1);
#pragma unroll
            for (int tu = 0; tu < 2; ++tu) {
                sa[tu] = (f32x4){0.f, 0.f, 0.f, 0.f};
                sa[tu] = __builtin_amdgcn_mfma_f32_16x16x32_f16(kf[tu][0], qf[0], sa[tu], 0, 0, 0);
                sa[tu] = __builtin_amdgcn_mfma_f32_16x16x32_f16(kf[tu][1], qf[1], sa[tu], 0, 0, 0);
            }
            __builtin_amdgcn_s_setprio(0);

            float wv[2][4];
#pragma unroll
            for (int tu = 0; tu < 2; ++tu)
#pragma unroll
                for (int r = 0; r < 4; ++r) {
                    float tv = sa[tu][r];
                    if (slow) {
                        const int kp = (hf * 2 + tu) * 16 + g * 4 + r;
                        if (((jt == jtd) & (kp == rel)) | (j0 + kp >= cb))
                            tv = -1e30f;
                    }
                    wv[tu][r] = exp2f(tv);     // -1e30 -> 0
                }
            lrun += ((wv[0][0] + wv[0][1]) + (wv[0][2] + wv[0][3]))
                  + ((wv[1][0] + wv[1][1]) + (wv[1][2] + wv[1][3]));

            half8 pf;
            pf[0] = (_Float16)wv[0][0]; pf[1] = (_Float16)wv[0][1];
            pf[2] = (_Float16)wv[0][2]; pf[3] = (_Float16)wv[0][3];
            pf[4] = (_Float16)wv[1][0]; pf[5] = (_Float16)wv[1][1];
            pf[6] = (_Float16)wv[1][2]; pf[7] = (_Float16)wv[1][3];

            __builtin_amdgcn_s_setprio(1);
#pragma unroll
            for (int dd = 0; dd < 4; ++dd) {
                const int row = dd * 16 + ln;
                const int sw  = (row & 7) << 4;
                const int rb  = row * 128;
                // kappa-permuted V storage: fragment = one contiguous b128
                const half8 vf = *(const half8*)(vb + ((rb + hf * 64 + g * 16) ^ sw));
                oacc[dd] = __builtin_amdgcn_mfma_f32_16x16x32_f16(vf, pf, oacc[dd], 0, 0, 0);
            }
            __builtin_amdgcn_s_setprio(0);
        }
        cur ^= 1;
    }

    // epilogue: combine pair halves via LDS (fixed-ref softmax is linear in keys)
    __syncthreads();                           // all staging/reads done; reuse LDS
    f32x4* cmo = (f32x4*)ksm;                  // [4 pair][4 dd][64 lane] f32x4 = 16KB
    float*  cml = (float*)vsm;                 // [4 pair][64 lane] float
    if (active && hf == 1) {
#pragma unroll
        for (int dd = 0; dd < 4; ++dd) cmo[(p * 4 + dd) * 64 + l] = oacc[dd];
        cml[p * 64 + l] = lrun;
    }
    __syncthreads();
    if (active && hf == 0) {
#pragma unroll
        for (int dd = 0; dd < 4; ++dd) oacc[dd] += cmo[(p * 4 + dd) * 64 + l];
        float ls = lrun + cml[p * 64 + l];
        ls += __shfl_xor(ls, 16);
        ls += __shfl_xor(ls, 32);
        const int iq = qw + ln;
        if (iq < cb) {
            const float inv = (ls > 0.f) ? 1.f / ls : 0.f;
            _Float16* op = Oc + ((size_t)((b << 11) + iq)) * HH + h * HD + g * 4;
#pragma unroll
            for (int dd = 0; dd < 4; ++dd) {
                half4v hv;
#pragma unroll
                for (int r = 0; r < 4; ++r) hv[r] = (_Float16)(oacc[dd][r] * inv);
                *(half4v*)(op + dd * 16) = hv;
            }
        }
    }
}

// ---------------- launch ----------------
extern "C" void kernel_launch(void* const* d_in, const int* in_sizes, int n_in,
                              void* d_out, int out_size, void* d_ws, size_t ws_size,
                              hipStream_t stream)
{
    (void)in_sizes; (void)n_in; (void)out_size; (void)ws_size;

    const float* x  = (const float*)d_in[0];
    const int*   mk = (const int*)d_in[1];
    const float* Wq = (const float*)d_in[2];
    const float* bq = (const float*)d_in[3];
    const float* Wk = (const float*)d_in[4];
    const float* bk = (const float*)d_in[5];
    const float* Wv = (const float*)d_in[6];
    const float* bv = (const float*)d_in[7];
    const float* Wc = (const float*)d_in[8];
    float* out = (float*)d_out;

    const int M = BB * SS;                    // 8192
    const size_t NE = (size_t)M * HH;
    const size_t NW = (size_t)HH * HH;
    _Float16* xc  = (_Float16*)d_ws;          // NE
    _Float16* W16 = xc + NE;                  // 4*NW (q,k,v contiguous; then c)
    _Float16* Qh  = W16 + 4 * NW;
    _Float16* Kh  = Qh + NE;
    _Float16* Vt  = Kh + NE;
    _Float16* Oc  = Vt + NE;
    int* vidx  = (int*)(Oc + NE);             // M ints
    int* cnt   = vidx + M;                    // 4 ints (+pad)
    int* ividx = cnt + 64;                    // M ints

    scan_mask<<<BB, 256, 0, stream>>>(mk, vidx, ividx, cnt);
    prep_rows<<<M + 2048, 256, 0, stream>>>(x, vidx, ividx, cnt, xc, out,
                                            Wq, Wk, Wv, Wc, W16);

    dim3 gq(3 * HH / 256, M / 256);           // (12, 32): actives = low y ids
    gemm_qkv<<<gq, 512, 0, stream>>>(xc, W16, bq, bk, bv, cnt, Qh, Kh, Vt);

    dim3 ga(BB * NH, SS / 64);                // (64, 32): bh fastest, ~half exit
    attn_mfma<<<ga, 512, 0, stream>>>(Qh, Kh, Vt, cnt, Oc);

    dim3 go(HH / 128, M / 128);               // (8, 64): actives = low y ids
    gemm_out<<<go, 256, 0, stream>>>(Oc, W16 + 3 * NW, cnt, vidx, out);
}